// Round 1
// baseline (964.878 us; speedup 1.0000x reference)
//
#include <hip/hip_runtime.h>
#include <hip/hip_bf16.h>

typedef __bf16 bf16;
typedef __bf16 bf16x4 __attribute__((ext_vector_type(4)));
typedef __bf16 bf16x8 __attribute__((ext_vector_type(8)));
typedef float  f32x4  __attribute__((ext_vector_type(4)));

#define B_SZ   16
#define T_SZ   4096
#define NFREQ  512
#define NFFT   1024
#define HOP    512
#define OUT_LEN 2097664   // (4096-1)*512 + 1024

#define BM 128
#define BN 128
#define BK 32
#define KTOT 1024
#define NSTEP (KTOT / BK)   // 32
#define LDB (BK + 8)        // padded row: 40 bf16 = 80 B, kills power-of-2 bank aliasing

// frames[b][j][t] = (sum_f magn[b,f,t]*rk[j,f] + sum_f phase[b,f,t]*ik[j,f] + ac[b,t]) / 1024
// out[b][t*512 + j] += frames[b][j][t]   (each out elem gets exactly 2 contributions)
__global__ __launch_bounds__(256, 2) void istft_gemm_ola(
    const float* __restrict__ magn, const float* __restrict__ phase,
    const float* __restrict__ acv,
    const float* __restrict__ rk,  const float* __restrict__ ik,
    float* __restrict__ out)
{
    // double-buffered padded tiles: A = W[j][k], B = X^T[t][k]
    __shared__ __attribute__((aligned(16))) bf16 As[2][BM * LDB];
    __shared__ __attribute__((aligned(16))) bf16 Bs[2][BN * LDB];

    const int tid = threadIdx.x;
    const int w   = tid >> 6;     // wave 0..3
    const int l   = tid & 63;

    const int bid = blockIdx.x;
    const int b   = bid >> 8;     // 16 batches
    const int r   = bid & 255;
    const int jt  = r & 7;        // 8 j-tiles (adjacent bids share the B-panel)
    const int tt  = r >> 3;       // 32 t-tiles
    const int j0  = jt * BM;
    const int t0  = tt * BN;

    const float* xm = magn  + (size_t)b * NFREQ * T_SZ;
    const float* xp = phase + (size_t)b * NFREQ * T_SZ;

    // ---- staging thread maps ----
    // A: 128 rows x 32 f32: thread -> (jrow = tid>>3 in 0..31, fc = (tid&7)*4), 4 row-passes
    const int jrow = tid >> 3;
    const int fc   = (tid & 7) * 4;
    // B: 32 f-rows x 128 t f32: thread -> (f0 = (tid>>5)*4, tl = tid&31), t covered at tl+32i
    const int f0 = (tid >> 5) * 4;
    const int tl = tid & 31;

    f32x4 areg[4];
    float vreg[4][4];   // [fj][i]

    f32x4 acc[4][4];
    #pragma unroll
    for (int i = 0; i < 4; ++i)
        #pragma unroll
        for (int j = 0; j < 4; ++j)
            acc[i][j] = (f32x4){0.f, 0.f, 0.f, 0.f};

    const int mbase = (w & 1) * 64;
    const int nbase = (w >> 1) * 64;

    auto loadA = [&](int ks) {
        const int k0 = ks * BK;
        const float* wsrc = (k0 < NFREQ) ? (rk + k0) : (ik + (k0 - NFREQ));
        #pragma unroll
        for (int i = 0; i < 4; ++i)
            areg[i] = *(const f32x4*)&wsrc[(size_t)(j0 + jrow + 32 * i) * NFREQ + fc];
    };
    auto writeA = [&](int p) {
        #pragma unroll
        for (int i = 0; i < 4; ++i) {
            bf16x4 v;
            v[0] = (bf16)areg[i][0]; v[1] = (bf16)areg[i][1];
            v[2] = (bf16)areg[i][2]; v[3] = (bf16)areg[i][3];
            *(bf16x4*)&As[p][(jrow + 32 * i) * LDB + fc] = v;
        }
    };
    auto loadB = [&](int ks) {
        const int k0 = ks * BK;   // all 32 f's of a step are on one side of the 512 split
        const float* xb = (k0 < NFREQ) ? (xm + (size_t)k0 * T_SZ)
                                       : (xp + (size_t)(k0 - NFREQ) * T_SZ);
        #pragma unroll
        for (int fj = 0; fj < 4; ++fj)
            #pragma unroll
            for (int i = 0; i < 4; ++i)
                vreg[fj][i] = xb[(size_t)(f0 + fj) * T_SZ + t0 + tl + 32 * i];
    };
    auto writeB = [&](int p) {
        #pragma unroll
        for (int i = 0; i < 4; ++i) {
            bf16x4 v;
            v[0] = (bf16)vreg[0][i]; v[1] = (bf16)vreg[1][i];
            v[2] = (bf16)vreg[2][i]; v[3] = (bf16)vreg[3][i];
            *(bf16x4*)&Bs[p][(tl + 32 * i) * LDB + f0] = v;
        }
    };

    // prologue: fill buffer 0
    loadA(0); loadB(0);
    writeA(0); writeB(0);
    __syncthreads();

    int p = 0;
    for (int ks = 0; ks < NSTEP; ++ks) {
        if (ks + 1 < NSTEP) { loadA(ks + 1); loadB(ks + 1); }  // issue next-tile global loads

        // compute current buffer
        bf16x8 af[4], bf[4];
        #pragma unroll
        for (int mi = 0; mi < 4; ++mi)
            af[mi] = *(const bf16x8*)&As[p][(mbase + mi * 16 + (l & 15)) * LDB + (l >> 4) * 8];
        #pragma unroll
        for (int ni = 0; ni < 4; ++ni)
            bf[ni] = *(const bf16x8*)&Bs[p][(nbase + ni * 16 + (l & 15)) * LDB + (l >> 4) * 8];
        #pragma unroll
        for (int mi = 0; mi < 4; ++mi)
            #pragma unroll
            for (int ni = 0; ni < 4; ++ni)
                acc[mi][ni] = __builtin_amdgcn_mfma_f32_16x16x32_bf16(
                    af[mi], bf[ni], acc[mi][ni], 0, 0, 0);

        if (ks + 1 < NSTEP) { writeA(p ^ 1); writeB(p ^ 1); }  // cvt + LDS write next buffer
        __syncthreads();
        p ^= 1;
    }

    // epilogue: frames -> overlap-add via atomics. out[n] gets (j=n&511,t) and (j+512,t-1).
    const float inv = 1.0f / 1024.0f;
    float* ob = out + (size_t)b * OUT_LEN;
    const float* acb = acv + b * T_SZ;
    #pragma unroll
    for (int ni = 0; ni < 4; ++ni) {
        const int t = t0 + nbase + ni * 16 + (l & 15);   // C/D: col = lane&15
        const float act = acb[t];
        const int ot = t * HOP;
        #pragma unroll
        for (int mi = 0; mi < 4; ++mi) {
            const int j = j0 + mbase + mi * 16 + (l >> 4) * 4;  // row = (lane>>4)*4 + reg
            #pragma unroll
            for (int rr = 0; rr < 4; ++rr) {
                const float v = (acc[mi][ni][rr] + act) * inv;
                unsafeAtomicAdd(&ob[ot + j + rr], v);
            }
        }
    }
}

extern "C" void kernel_launch(void* const* d_in, const int* in_sizes, int n_in,
                              void* d_out, int out_size, void* d_ws, size_t ws_size,
                              hipStream_t stream) {
    const float* magn  = (const float*)d_in[0];
    const float* phase = (const float*)d_in[1];
    const float* ac    = (const float*)d_in[2];
    const float* rk    = (const float*)d_in[3];
    const float* ik    = (const float*)d_in[4];
    float* out = (float*)d_out;

    // harness poisons d_out before timing and never re-zeros between replays
    hipMemsetAsync(out, 0, (size_t)out_size * sizeof(float), stream);

    const int grid = B_SZ * (NFFT / BM) * (T_SZ / BN);  // 16*8*32 = 4096
    istft_gemm_ola<<<grid, 256, 0, stream>>>(magn, phase, ac, rk, ik, out);
}

// Round 2
// 579.532 us; speedup vs baseline: 1.6649x; 1.6649x over previous
//
#include <hip/hip_runtime.h>
#include <hip/hip_bf16.h>

typedef __bf16 bf16;
typedef __bf16 bf16x4 __attribute__((ext_vector_type(4)));
typedef __bf16 bf16x8 __attribute__((ext_vector_type(8)));
typedef float  f32x4  __attribute__((ext_vector_type(4)));

#define B_SZ   16
#define T_SZ   4096
#define NFREQ  512
#define HOP    512
#define OUT_LEN 2097664   // 4097 * 512
#define NTT    33         // 33 t-tiles of 128 cover tt in [0,4097)

#define BN 128            // t columns per block
#define BK 32
#define NSTEP 32          // K = 1024 (512 magn + 512 phase)
#define LDB 40            // padded LDS row (bf16): 80 B, breaks pow2 bank aliasing

// out[b][tt*512+jl] = ( dot(W[jl],X[tt]) + ac[tt] + dot(W[jl+512],X[tt-1]) + ac[tt-1] ) / 1024
// Block = output tile 64 jl x 128 tt. A-tile rows: 64 lo (j0..) + 64 hi (j0+512..).
// B-tile: 129 t-rows (t0-1 .. t0+127), zero-filled outside [0,4096).
__global__ __launch_bounds__(256, 2) void istft_fused(
    const float* __restrict__ magn, const float* __restrict__ phase,
    const float* __restrict__ acv,
    const float* __restrict__ rk,  const float* __restrict__ ik,
    float* __restrict__ out)
{
    __shared__ __attribute__((aligned(16))) bf16 As[2][128 * LDB];
    __shared__ __attribute__((aligned(16))) bf16 Bs[2][129 * LDB];

    const int tid = threadIdx.x;
    const int w   = tid >> 6;      // wave 0..3, each owns 32 t-cols
    const int l   = tid & 63;

    // XCD-co-resident decode: the 8 j-blocks of a panel share bid%8 == panel%8
    const int bid  = blockIdx.x;
    const int xcd  = bid & 7;
    const int q    = bid >> 3;
    const int jt   = q & 7;        // 8 j-tiles of 64
    const int pgrp = q >> 3;       // 0..65
    const int pnl  = pgrp * 8 + xcd;   // 0..527
    const int b    = pnl / NTT;
    const int tt0  = pnl - b * NTT;
    const int j0   = jt * 64;
    const int t0   = tt0 * BN;

    const float* xm = magn  + (size_t)b * NFREQ * T_SZ;
    const float* xp = phase + (size_t)b * NFREQ * T_SZ;

    // staging maps
    const int jrow = tid >> 3;          // A: 32 rows/pass x 4 passes
    const int fc   = (tid & 7) * 4;     // A: 8 f-groups of 4
    const int f0   = (tid >> 5) * 4;    // B: 8 f-groups of 4
    const int tl   = tid & 31;          // B: 32 t/pass x 4 passes

    f32x4 areg[4];
    float vreg[4][4];    // [fj][pass]
    float rz = 0.f;      // row 0 (t0-1) staging value, threads tid<32

    f32x4 acc[8][2];     // mi 0..3 = lo GEMM, 4..7 = hi GEMM; ni = 2 col-frags
    #pragma unroll
    for (int i = 0; i < 8; ++i)
        #pragma unroll
        for (int j = 0; j < 2; ++j)
            acc[i][j] = (f32x4){0.f, 0.f, 0.f, 0.f};

    const int nbase = w * 32;

    auto loadA = [&](int ks) {
        const int k0 = ks * BK;
        const float* wsrc = (k0 < NFREQ) ? (rk + k0) : (ik + (k0 - NFREQ));
        #pragma unroll
        for (int i = 0; i < 4; ++i) {
            const int jr = jrow + 32 * i;                 // tile row 0..127
            const int j  = (jr < 64) ? (j0 + jr) : (j0 + 448 + jr);  // lo | hi(+512)
            areg[i] = *(const f32x4*)&wsrc[(size_t)j * NFREQ + fc];
        }
    };
    auto writeA = [&](int p) {
        #pragma unroll
        for (int i = 0; i < 4; ++i) {
            bf16x4 v;
            v[0] = (bf16)areg[i][0]; v[1] = (bf16)areg[i][1];
            v[2] = (bf16)areg[i][2]; v[3] = (bf16)areg[i][3];
            *(bf16x4*)&As[p][(jrow + 32 * i) * LDB + fc] = v;
        }
    };
    auto loadB = [&](int ks) {
        const int k0 = ks * BK;   // each 32-f step is entirely on one side of the 512 split
        const float* xb = (k0 < NFREQ) ? (xm + (size_t)k0 * T_SZ)
                                       : (xp + (size_t)(k0 - NFREQ) * T_SZ);
        #pragma unroll
        for (int i = 0; i < 4; ++i) {
            if (t0 + 32 * i + 32 <= T_SZ) {        // uniform validity per pass
                #pragma unroll
                for (int fj = 0; fj < 4; ++fj)
                    vreg[fj][i] = xb[(size_t)(f0 + fj) * T_SZ + t0 + tl + 32 * i];
            } else {
                #pragma unroll
                for (int fj = 0; fj < 4; ++fj)
                    vreg[fj][i] = 0.f;
            }
        }
        if (tid < BK)   // row 0: t = t0-1 (zero when t0==0)
            rz = (t0 >= 1) ? xb[(size_t)tid * T_SZ + (t0 - 1)] : 0.f;
    };
    auto writeB = [&](int p) {
        #pragma unroll
        for (int i = 0; i < 4; ++i) {
            bf16x4 v;
            v[0] = (bf16)vreg[0][i]; v[1] = (bf16)vreg[1][i];
            v[2] = (bf16)vreg[2][i]; v[3] = (bf16)vreg[3][i];
            *(bf16x4*)&Bs[p][(1 + tl + 32 * i) * LDB + f0] = v;
        }
        if (tid < BK) Bs[p][tid] = (bf16)rz;       // row 0, k = tid
    };

    loadA(0); loadB(0);
    writeA(0); writeB(0);
    __syncthreads();

    int p = 0;
    for (int ks = 0; ks < NSTEP; ++ks) {
        if (ks + 1 < NSTEP) { loadA(ks + 1); loadB(ks + 1); }

        bf16x8 af[8], bl[2], bh[2];
        #pragma unroll
        for (int mi = 0; mi < 8; ++mi)
            af[mi] = *(const bf16x8*)&As[p][(mi * 16 + (l & 15)) * LDB + (l >> 4) * 8];
        #pragma unroll
        for (int ni = 0; ni < 2; ++ni) {
            const int rb = nbase + ni * 16 + (l & 15);
            bh[ni] = *(const bf16x8*)&Bs[p][rb * LDB + (l >> 4) * 8];        // t = tt-1
            bl[ni] = *(const bf16x8*)&Bs[p][(rb + 1) * LDB + (l >> 4) * 8];  // t = tt
        }
        #pragma unroll
        for (int ni = 0; ni < 2; ++ni)
            #pragma unroll
            for (int mi = 0; mi < 4; ++mi) {
                acc[mi][ni] = __builtin_amdgcn_mfma_f32_16x16x32_bf16(
                    af[mi], bl[ni], acc[mi][ni], 0, 0, 0);
                acc[mi + 4][ni] = __builtin_amdgcn_mfma_f32_16x16x32_bf16(
                    af[mi + 4], bh[ni], acc[mi + 4][ni], 0, 0, 0);
            }

        if (ks + 1 < NSTEP) { writeA(p ^ 1); writeB(p ^ 1); }
        __syncthreads();
        p ^= 1;
    }

    // epilogue: combine lo + hi + ac terms, plain streaming stores (each out elem once)
    const float inv = 1.0f / 1024.0f;
    float* ob = out + (size_t)b * OUT_LEN;
    const float* acb = acv + (size_t)b * T_SZ;
    #pragma unroll
    for (int ni = 0; ni < 2; ++ni) {
        const int tt = t0 + nbase + ni * 16 + (l & 15);
        if (tt <= T_SZ) {
            float acs = 0.f;
            if (tt < T_SZ) acs += acb[tt];
            if (tt >= 1)   acs += acb[tt - 1];
            #pragma unroll
            for (int mi = 0; mi < 4; ++mi) {
                const int jl = j0 + mi * 16 + (l >> 4) * 4;   // C/D: row=(l>>4)*4+reg
                f32x4 v;
                #pragma unroll
                for (int rr = 0; rr < 4; ++rr)
                    v[rr] = (acc[mi][ni][rr] + acc[mi + 4][ni][rr] + acs) * inv;
                __builtin_nontemporal_store(v, (f32x4*)&ob[(size_t)tt * HOP + jl]);
            }
        }
    }
}

extern "C" void kernel_launch(void* const* d_in, const int* in_sizes, int n_in,
                              void* d_out, int out_size, void* d_ws, size_t ws_size,
                              hipStream_t stream) {
    const float* magn  = (const float*)d_in[0];
    const float* phase = (const float*)d_in[1];
    const float* ac    = (const float*)d_in[2];
    const float* rk    = (const float*)d_in[3];
    const float* ik    = (const float*)d_in[4];
    float* out = (float*)d_out;

    const int grid = 66 * 8 * 8;   // 528 panels (16 b x 33 t-tiles) x 8 j-tiles
    istft_fused<<<grid, 256, 0, stream>>>(magn, phase, ac, rk, ik, out);
}

// Round 3
// 252.093 us; speedup vs baseline: 3.8275x; 2.2989x over previous
//
#include <hip/hip_runtime.h>
#include <hip/hip_bf16.h>

typedef __bf16 bf16;
typedef __bf16 bf16x4 __attribute__((ext_vector_type(4)));
typedef __bf16 bf16x8 __attribute__((ext_vector_type(8)));
typedef float  f32x4  __attribute__((ext_vector_type(4)));

#define T_SZ   4096
#define NFREQ  512
#define HOP    512
#define OUT_LEN 2097664   // 4097 * 512
#define NTT    33         // t-tiles of 128 covering tt in [0,4097)

#define XW_ELEMS ((size_t)16 * 4096 * 1024)
#define WT_ELEMS ((size_t)1024 * 1024)
#define WS_NEED  ((XW_ELEMS + WT_ELEMS) * 2)

// async global->LDS, 16B per lane; LDS dest is wave-uniform base + lane*16
__device__ __forceinline__ void gl16(const void* g, void* l) {
    __builtin_amdgcn_global_load_lds(
        (const __attribute__((address_space(1))) void*)g,
        (__attribute__((address_space(3))) void*)l, 16, 0, 0);
}

// ---------- pre-convert weights: Wt[j][k] = k<512 ? rk[j][k] : ik[j][k-512] ----------
__global__ __launch_bounds__(256, 4) void cvt_w(const float* __restrict__ rk,
                                                const float* __restrict__ ik,
                                                bf16* __restrict__ Wt) {
    const int j  = blockIdx.x;
    const int k4 = threadIdx.x * 4;
    const float* s = (k4 < NFREQ) ? &rk[j * NFREQ + k4] : &ik[j * NFREQ + k4 - NFREQ];
    f32x4 v = *(const f32x4*)s;
    bf16x4 h;
    h[0] = (bf16)v[0]; h[1] = (bf16)v[1]; h[2] = (bf16)v[2]; h[3] = (bf16)v[3];
    *(bf16x4*)&Wt[((size_t)j << 10) + k4] = h;
}

// ---------- pre-convert + transpose X: Xw[b][t][k] = (k<512?magn:phase)[b][k%512][t] ----------
__global__ __launch_bounds__(256, 4) void cvt_x(const float* __restrict__ magn,
                                                const float* __restrict__ phase,
                                                bf16* __restrict__ Xw) {
    __shared__ bf16 t2[64][132];   // [f][t], t padded 128->132 (row 264 B: 8-aligned, bank-spread)
    const int tid = threadIdx.x;
    const int bid = blockIdx.x;
    const int kt  = bid & 15;           // 16 k-tiles of 64
    const int tt  = (bid >> 4) & 31;    // 32 t-tiles of 128
    const int b   = bid >> 9;           // 16 batches
    const float* src = (kt < 8 ? magn : phase)
                     + ((size_t)b * NFREQ + (kt & 7) * 64) * T_SZ + tt * 128;
    // read coalesced along t, cvt, store [f][t]
    const int fr = tid >> 5;
    const int c  = (tid & 31) * 4;
    #pragma unroll
    for (int p = 0; p < 8; ++p) {
        const int f = fr + 8 * p;
        f32x4 v = *(const f32x4*)&src[(size_t)f * T_SZ + c];
        bf16x4 h;
        h[0] = (bf16)v[0]; h[1] = (bf16)v[1]; h[2] = (bf16)v[2]; h[3] = (bf16)v[3];
        *(bf16x4*)&t2[f][c] = h;
    }
    __syncthreads();
    // gather k-contiguous chunks, write coalesced along k
    const int koff = (tid & 7) * 8;
    bf16* dstb = Xw + (((size_t)b * T_SZ + tt * 128) << 10) + kt * 64 + koff;
    #pragma unroll
    for (int q = 0; q < 4; ++q) {
        const int tr = (tid >> 3) + 32 * q;
        bf16x8 o;
        #pragma unroll
        for (int ki = 0; ki < 8; ++ki) o[ki] = t2[koff + ki][tr];
        *(bf16x8*)&dstb[(size_t)tr << 10] = o;
    }
}

// ---------- fused GEMM + overlap-add, all-gload_lds staging ----------
// Block: output tile 64 j x 128 t. A rows 0..63 = Wt[j0+r], 64..127 = Wt[j0+512+(r-64)].
// Bs rows i=0..128 <-> t = t0-1+i (row 0 zeroed when t0==0, clamped at tail).
__global__ __launch_bounds__(256, 3) void istft_gemm(
    const bf16* __restrict__ Xw, const bf16* __restrict__ Wt,
    const float* __restrict__ acv, float* __restrict__ out)
{
    __shared__ __attribute__((aligned(16))) bf16 As[2][128 * 32];
    __shared__ __attribute__((aligned(16))) bf16 Bs[2][129 * 32];

    const int tid = threadIdx.x;
    const int w   = tid >> 6;
    const int l   = tid & 63;

    const int bid  = blockIdx.x;
    const int xcd  = bid & 7;
    const int q    = bid >> 3;
    const int jt   = q & 7;
    const int pgrp = q >> 3;
    const int pnl  = pgrp * 8 + xcd;     // 0..527, same-panel blocks share bid%8 (same XCD)
    const int b    = pnl / NTT;
    const int tt0  = pnl - b * NTT;
    const int j0   = jt * 64;
    const int t0   = tt0 * 128;
    const size_t bb = (size_t)b * T_SZ;

    f32x4 acc[8][2];
    #pragma unroll
    for (int i = 0; i < 8; ++i)
        #pragma unroll
        for (int j = 0; j < 2; ++j)
            acc[i][j] = (f32x4){0.f, 0.f, 0.f, 0.f};
    const int nbase = w * 32;

    // zero t0-1 row (both buffers) when it's out of range
    if (t0 == 0 && tid < 64) Bs[tid >> 5][tid & 31] = (bf16)0.f;

    const int koff = (l & 3) * 8;   // bf16 elems within 64B row
    const int rsub = l >> 2;        // row within 16-row chunk

    auto stage = [&](int p, int ks) {
        const int k0 = ks * 32;
        // A: lo rows 16w.., hi rows 64+16w..
        gl16(Wt + (((size_t)(j0 + 16 * w + rsub)) << 10) + k0 + koff,
             &As[p][(16 * w) * 32]);
        gl16(Wt + (((size_t)(j0 + 512 + 16 * w + rsub)) << 10) + k0 + koff,
             &As[p][(64 + 16 * w) * 32]);
        // B: rows 1+16w.. (t = t0+16w+..), 65+16w.. (t = t0+64+16w+..), clamp tail
        int t1 = t0 + 16 * w + rsub;      if (t1 > T_SZ - 1) t1 = T_SZ - 1;
        gl16(Xw + ((bb + t1) << 10) + k0 + koff, &Bs[p][(1 + 16 * w) * 32]);
        int t2 = t0 + 64 + 16 * w + rsub; if (t2 > T_SZ - 1) t2 = T_SZ - 1;
        gl16(Xw + ((bb + t2) << 10) + k0 + koff, &Bs[p][(65 + 16 * w) * 32]);
        // row 0: t = t0-1 (4 lanes, 64 B)
        if (w == 0 && t0 > 0 && l < 4)
            gl16(Xw + ((bb + t0 - 1) << 10) + k0 + l * 8, &Bs[p][0]);
    };

    stage(0, 0);
    __syncthreads();

    int p = 0;
    for (int ks = 0; ks < 32; ++ks) {
        if (ks + 1 < 32) stage(p ^ 1, ks + 1);

        bf16x8 af[8], bl[2], bh[2];
        #pragma unroll
        for (int mi = 0; mi < 8; ++mi)
            af[mi] = *(const bf16x8*)&As[p][(mi * 16 + (l & 15)) * 32 + (l >> 4) * 8];
        #pragma unroll
        for (int ni = 0; ni < 2; ++ni) {
            const int r = nbase + ni * 16 + (l & 15);
            bh[ni] = *(const bf16x8*)&Bs[p][r * 32 + (l >> 4) * 8];          // t = tt-1
            bl[ni] = *(const bf16x8*)&Bs[p][(r + 1) * 32 + (l >> 4) * 8];    // t = tt
        }
        #pragma unroll
        for (int ni = 0; ni < 2; ++ni)
            #pragma unroll
            for (int mi = 0; mi < 4; ++mi) {
                acc[mi][ni] = __builtin_amdgcn_mfma_f32_16x16x32_bf16(
                    af[mi], bl[ni], acc[mi][ni], 0, 0, 0);
                acc[mi + 4][ni] = __builtin_amdgcn_mfma_f32_16x16x32_bf16(
                    af[mi + 4], bh[ni], acc[mi + 4][ni], 0, 0, 0);
            }

        __syncthreads();
        p ^= 1;
    }

    // epilogue: out[tt*512+jl] = (lo + hi + ac[tt] + ac[tt-1]) / 1024, stored once
    const float inv = 1.0f / 1024.0f;
    float* ob = out + (size_t)b * OUT_LEN;
    const float* acb = acv + bb;
    #pragma unroll
    for (int ni = 0; ni < 2; ++ni) {
        const int tt = t0 + nbase + ni * 16 + (l & 15);
        if (tt <= T_SZ) {
            const bool lov = (tt < T_SZ);         // lo term invalid at tt==4096 (clamped B)
            float acs = (lov ? acb[tt] : 0.f) + (tt >= 1 ? acb[tt - 1] : 0.f);
            #pragma unroll
            for (int mi = 0; mi < 4; ++mi) {
                const int jl = j0 + mi * 16 + (l >> 4) * 4;
                f32x4 v;
                #pragma unroll
                for (int rr = 0; rr < 4; ++rr)
                    v[rr] = ((lov ? acc[mi][ni][rr] : 0.f) + acc[mi + 4][ni][rr] + acs) * inv;
                __builtin_nontemporal_store(v, (f32x4*)&ob[(size_t)tt * HOP + jl]);
            }
        }
    }
}

// ---------- fallback (round-2 kernel, used only if ws too small) ----------
#define LDBL 40
__global__ __launch_bounds__(256, 2) void istft_fused_legacy(
    const float* __restrict__ magn, const float* __restrict__ phase,
    const float* __restrict__ acv,
    const float* __restrict__ rk,  const float* __restrict__ ik,
    float* __restrict__ out)
{
    __shared__ __attribute__((aligned(16))) bf16 As[2][128 * LDBL];
    __shared__ __attribute__((aligned(16))) bf16 Bs[2][129 * LDBL];
    const int tid = threadIdx.x;
    const int w = tid >> 6, l = tid & 63;
    const int bid = blockIdx.x;
    const int xcd = bid & 7, q = bid >> 3;
    const int jt = q & 7, pgrp = q >> 3;
    const int pnl = pgrp * 8 + xcd;
    const int b = pnl / NTT, tt0 = pnl - b * NTT;
    const int j0 = jt * 64, t0 = tt0 * 128;
    const float* xm = magn  + (size_t)b * NFREQ * T_SZ;
    const float* xp = phase + (size_t)b * NFREQ * T_SZ;
    const int jrow = tid >> 3, fc = (tid & 7) * 4;
    const int f0 = (tid >> 5) * 4, tl = tid & 31;
    f32x4 areg[4]; float vreg[4][4]; float rz = 0.f;
    f32x4 acc[8][2];
    #pragma unroll
    for (int i = 0; i < 8; ++i)
        #pragma unroll
        for (int j = 0; j < 2; ++j) acc[i][j] = (f32x4){0.f, 0.f, 0.f, 0.f};
    const int nbase = w * 32;
    auto loadA = [&](int ks) {
        const int k0 = ks * 32;
        const float* wsrc = (k0 < NFREQ) ? (rk + k0) : (ik + (k0 - NFREQ));
        #pragma unroll
        for (int i = 0; i < 4; ++i) {
            const int jr = jrow + 32 * i;
            const int j = (jr < 64) ? (j0 + jr) : (j0 + 448 + jr);
            areg[i] = *(const f32x4*)&wsrc[(size_t)j * NFREQ + fc];
        }
    };
    auto writeA = [&](int p) {
        #pragma unroll
        for (int i = 0; i < 4; ++i) {
            bf16x4 v;
            v[0] = (bf16)areg[i][0]; v[1] = (bf16)areg[i][1];
            v[2] = (bf16)areg[i][2]; v[3] = (bf16)areg[i][3];
            *(bf16x4*)&As[p][(jrow + 32 * i) * LDBL + fc] = v;
        }
    };
    auto loadB = [&](int ks) {
        const int k0 = ks * 32;
        const float* xb = (k0 < NFREQ) ? (xm + (size_t)k0 * T_SZ)
                                       : (xp + (size_t)(k0 - NFREQ) * T_SZ);
        #pragma unroll
        for (int i = 0; i < 4; ++i) {
            if (t0 + 32 * i + 32 <= T_SZ) {
                #pragma unroll
                for (int fj = 0; fj < 4; ++fj)
                    vreg[fj][i] = xb[(size_t)(f0 + fj) * T_SZ + t0 + tl + 32 * i];
            } else {
                #pragma unroll
                for (int fj = 0; fj < 4; ++fj) vreg[fj][i] = 0.f;
            }
        }
        if (tid < 32) rz = (t0 >= 1) ? xb[(size_t)tid * T_SZ + (t0 - 1)] : 0.f;
    };
    auto writeB = [&](int p) {
        #pragma unroll
        for (int i = 0; i < 4; ++i) {
            bf16x4 v;
            v[0] = (bf16)vreg[0][i]; v[1] = (bf16)vreg[1][i];
            v[2] = (bf16)vreg[2][i]; v[3] = (bf16)vreg[3][i];
            *(bf16x4*)&Bs[p][(1 + tl + 32 * i) * LDBL + f0] = v;
        }
        if (tid < 32) Bs[p][tid] = (bf16)rz;
    };
    loadA(0); loadB(0); writeA(0); writeB(0);
    __syncthreads();
    int p = 0;
    for (int ks = 0; ks < 32; ++ks) {
        if (ks + 1 < 32) { loadA(ks + 1); loadB(ks + 1); }
        bf16x8 af[8], blv[2], bhv[2];
        #pragma unroll
        for (int mi = 0; mi < 8; ++mi)
            af[mi] = *(const bf16x8*)&As[p][(mi * 16 + (l & 15)) * LDBL + (l >> 4) * 8];
        #pragma unroll
        for (int ni = 0; ni < 2; ++ni) {
            const int rb = nbase + ni * 16 + (l & 15);
            bhv[ni] = *(const bf16x8*)&Bs[p][rb * LDBL + (l >> 4) * 8];
            blv[ni] = *(const bf16x8*)&Bs[p][(rb + 1) * LDBL + (l >> 4) * 8];
        }
        #pragma unroll
        for (int ni = 0; ni < 2; ++ni)
            #pragma unroll
            for (int mi = 0; mi < 4; ++mi) {
                acc[mi][ni] = __builtin_amdgcn_mfma_f32_16x16x32_bf16(af[mi], blv[ni], acc[mi][ni], 0, 0, 0);
                acc[mi + 4][ni] = __builtin_amdgcn_mfma_f32_16x16x32_bf16(af[mi + 4], bhv[ni], acc[mi + 4][ni], 0, 0, 0);
            }
        if (ks + 1 < 32) { writeA(p ^ 1); writeB(p ^ 1); }
        __syncthreads();
        p ^= 1;
    }
    const float inv = 1.0f / 1024.0f;
    float* ob = out + (size_t)b * OUT_LEN;
    const float* acb = acv + (size_t)b * T_SZ;
    #pragma unroll
    for (int ni = 0; ni < 2; ++ni) {
        const int tt = t0 + nbase + ni * 16 + (l & 15);
        if (tt <= T_SZ) {
            float acs = 0.f;
            if (tt < T_SZ) acs += acb[tt];
            if (tt >= 1)   acs += acb[tt - 1];
            #pragma unroll
            for (int mi = 0; mi < 4; ++mi) {
                const int jl = j0 + mi * 16 + (l >> 4) * 4;
                f32x4 v;
                #pragma unroll
                for (int rr = 0; rr < 4; ++rr)
                    v[rr] = (acc[mi][ni][rr] + acc[mi + 4][ni][rr] + acs) * inv;
                __builtin_nontemporal_store(v, (f32x4*)&ob[(size_t)tt * HOP + jl]);
            }
        }
    }
}

extern "C" void kernel_launch(void* const* d_in, const int* in_sizes, int n_in,
                              void* d_out, int out_size, void* d_ws, size_t ws_size,
                              hipStream_t stream) {
    const float* magn  = (const float*)d_in[0];
    const float* phase = (const float*)d_in[1];
    const float* ac    = (const float*)d_in[2];
    const float* rk    = (const float*)d_in[3];
    const float* ik    = (const float*)d_in[4];
    float* out = (float*)d_out;

    if (ws_size >= WS_NEED) {
        bf16* Xw = (bf16*)d_ws;
        bf16* Wt = Xw + XW_ELEMS;
        cvt_w<<<1024, 256, 0, stream>>>(rk, ik, Wt);
        cvt_x<<<8192, 256, 0, stream>>>(magn, phase, Xw);
        istft_gemm<<<528 * 8, 256, 0, stream>>>(Xw, Wt, ac, out);
    } else {
        istft_fused_legacy<<<528 * 8, 256, 0, stream>>>(magn, phase, ac, rk, ik, out);
    }
}